// Round 5
// baseline (72.653 us; speedup 1.0000x reference)
//
#include <hip/hip_runtime.h>
#include <math.h>

// E8S codebook quantization via bf16 MFMA, exact 3-way split, single pass.
//   scores[r][c] = 2*X[r]·G[c] - ||G[c]||^2 ; idx = first-argmax over c.
// Exactness: G coords are multiples of 0.25 (exact bf16); 2*X = h+m+l exact
// 3-term bf16 split; ||g||^2 is a multiple of 1/16 < 16 -> exact bf16, folded
// into the MFMA K-reduction as a 9th term paired with -1.0 on the X side
// (K-group 3, previously zeros). C operand = 0. One mfma_f32_16x16x32_bf16
// => biased 16x16 score tile, no separate bias load.
// Swapped operands (A=G, B=X): each lane's 4 D regs = 4 codewords of ONE row.
// Branchless argmax tracking (11 VALU/MFMA); global merge via packed u64
// atomicMax (ordered-score<<32 | ~idx) == np.argmax first-max semantics.

typedef short short8 __attribute__((ext_vector_type(8)));
typedef float f32x4  __attribute__((ext_vector_type(4)));

constexpr int NROWS  = 8192;
constexpr int NCW    = 55650;
constexpr int NTILE  = 3479;          // ceil(NCW/16)
constexpr int NCWP   = NTILE * 16;    // 55664 (pad scores driven very negative)
constexpr int NCHUNK = 128;           // codeword-tile chunks (grid.y)
constexpr int RB     = 16;            // row blocks of 512 rows (grid.x)

// workspace layout (bytes)
// Gb2: [NCWP][16] ushort — shorts 0..7 = bf16 coords, 8 = bf16 gn, 9..15 = 0
constexpr size_t OFF_GB2 = 0;
constexpr size_t OFF_XS  = OFF_GB2 + (size_t)NCWP * 32;  // ushort Xs[NROWS*4*8]
constexpr size_t OFF_B   = OFF_XS  + (size_t)NROWS * 64; // u64 best[NROWS]

__device__ inline unsigned short bf16_rne(float f) {
  unsigned int u = __float_as_uint(f);
  unsigned int r = u + 0x7FFFu + ((u >> 16) & 1u);
  return (unsigned short)(r >> 16);
}
__device__ inline float bf16_f(unsigned short h) {
  return __uint_as_float(((unsigned int)h) << 16);
}
__device__ inline unsigned int enc_ord(float f) {  // monotonic float->uint
  unsigned int u = __float_as_uint(f);
  return (u & 0x80000000u) ? ~u : (u | 0x80000000u);
}

__global__ __launch_bounds__(256) void e8_prep(
    const float* __restrict__ X, const float* __restrict__ G,
    const float* __restrict__ GN, unsigned short* __restrict__ Gb2,
    unsigned short* __restrict__ Xs, unsigned long long* __restrict__ best) {
  int i = blockIdx.x * 256 + threadIdx.x;
  if (i < NCWP) {
    unsigned short* g = Gb2 + (size_t)i * 16;
    if (i < NCW) {
      for (int j = 0; j < 8; ++j) g[j] = bf16_rne(G[(size_t)i*8+j]);
      g[8] = bf16_rne(GN[i]);           // exact: multiple of 1/16, < 16
      for (int j = 9; j < 16; ++j) g[j] = 0;
    } else {
      for (int j = 0; j < 8; ++j) g[j] = 0;
      g[8] = 0x7F7F;                    // bf16 max finite -> score ~ -3.4e38
      for (int j = 9; j < 16; ++j) g[j] = 0;
    }
  } else if (i < NCWP + NROWS) {
    int r = i - NCWP;
    for (int j = 0; j < 8; ++j) {
      float s = 2.0f * X[(size_t)r*8+j];           // exact
      unsigned short h = bf16_rne(s);  float r1 = s  - bf16_f(h);  // exact
      unsigned short m = bf16_rne(r1); float r2 = r1 - bf16_f(m);  // exact
      unsigned short l = bf16_rne(r2);             // residual after 3 terms = 0
      Xs[((size_t)r*4 + 0)*8 + j] = h;
      Xs[((size_t)r*4 + 1)*8 + j] = m;
      Xs[((size_t)r*4 + 2)*8 + j] = l;
      Xs[((size_t)r*4 + 3)*8 + j] = (j == 0) ? (unsigned short)0xBF80 : 0;  // -1.0
    }
    best[r] = 0ull;   // below enc_ord of any real score
  }
}

// Per block: 4 waves x 8 row-tiles = 512 rows, one chunk of ~27 codeword tiles.
// Lane roles: c = lane&15 (codeword-in-tile AND X-row-in-tile), kg = lane>>4.
// A-fragment: kg 0..2 load the coord slice (same bytes -> K-replication),
// kg 3 loads the [gn, 0...] slice.
__global__ __launch_bounds__(256, 4) void e8_main(
    const unsigned short* __restrict__ Gb2,
    const unsigned short* __restrict__ Xs,
    unsigned long long* __restrict__ best) {
  const int lane = threadIdx.x & 63;
  const int wave = threadIdx.x >> 6;
  const int c = lane & 15, kg = lane >> 4;
  const int rt0 = blockIdx.x * 32 + wave * 8;

  short8 xf[8];
#pragma unroll
  for (int t = 0; t < 8; ++t) {
    int row = (rt0 + t) * 16 + c;
    xf[t] = *reinterpret_cast<const short8*>(Xs + ((size_t)row*4 + kg)*8);
  }

  const int ct0 = (blockIdx.y * NTILE) / NCHUNK;
  const int ct1 = ((blockIdx.y + 1) * NTILE) / NCHUNK;

  float b[8]; int bi[8];
#pragma unroll
  for (int t = 0; t < 8; ++t) { b[t] = -INFINITY; bi[t] = 0; }

  const f32x4 cz = {0.f, 0.f, 0.f, 0.f};
  // per-lane A-slice offset within a tile row-block (ushort units)
  const size_t gboff = (size_t)c * 16 + (kg == 3 ? 8 : 0);

  short8 af = *reinterpret_cast<const short8*>(Gb2 + (size_t)ct0 * 256 + gboff);

  for (int ct = ct0; ct < ct1; ++ct) {
    const int ctn = (ct + 1 < ct1) ? ct + 1 : ct0;   // clamped prefetch
    short8 afn = *reinterpret_cast<const short8*>(Gb2 + (size_t)ctn * 256 + gboff);
    const int c3 = ct * 4 + 3, c2 = c3 - 1, c1 = c3 - 2, c0 = c3 - 3;  // SALU
#pragma unroll
    for (int t = 0; t < 8; ++t) {
      f32x4 d = __builtin_amdgcn_mfma_f32_16x16x32_bf16(af, xf[t], cz, 0, 0, 0);
      float m = fmaxf(fmaxf(d[0], d[1]), fmaxf(d[2], d[3]));
      int cand = c3;
      cand = (d[2] == m) ? c2 : cand;   // downward chain -> smallest slot wins
      cand = (d[1] == m) ? c1 : cand;
      cand = (d[0] == m) ? c0 : cand;
      const bool imp = m > b[t];        // strict > -> earliest tile wins
      b[t]  = imp ? m : b[t];
      bi[t] = imp ? cand : bi[t];
    }
    af = afn;
  }

#pragma unroll
  for (int t = 0; t < 8; ++t) {
    const int gi = ((bi[t] >> 2) << 4) + kg * 4 + (bi[t] & 3);  // global cw idx
    unsigned long long key =
        ((unsigned long long)enc_ord(b[t]) << 32) | (unsigned int)(~gi);
    unsigned long long o = __shfl_xor(key, 16, 64); key = (o > key) ? o : key;
    o = __shfl_xor(key, 32, 64);                    key = (o > key) ? o : key;
    if (lane < 16) atomicMax(&best[(size_t)(rt0 + t) * 16 + c], key);
  }
}

__global__ __launch_bounds__(256) void e8_final(
    const float* __restrict__ G, const unsigned long long* __restrict__ best,
    float* __restrict__ out) {
  const int r = blockIdx.x * 256 + threadIdx.x;
  const int idx = (int)(~(unsigned int)(best[r] & 0xFFFFFFFFull));
  const float4* g = reinterpret_cast<const float4*>(G + (size_t)idx * 8);
  float4 v0 = g[0], v1 = g[1];
  float4* o = reinterpret_cast<float4*>(out + (size_t)r * 8);
  o[0] = v0; o[1] = v1;
  out[(size_t)NROWS * 8 + r] = (float)(idx - 32768);
}

extern "C" void kernel_launch(void* const* d_in, const int* in_sizes, int n_in,
                              void* d_out, int out_size, void* d_ws, size_t ws_size,
                              hipStream_t stream) {
  const float* X  = (const float*)d_in[0];
  const float* G  = (const float*)d_in[1];
  const float* GN = (const float*)d_in[2];
  float* out = (float*)d_out;

  char* ws = (char*)d_ws;
  unsigned short*     Gb2  = (unsigned short*)(ws + OFF_GB2);
  unsigned short*     Xs   = (unsigned short*)(ws + OFF_XS);
  unsigned long long* best = (unsigned long long*)(ws + OFF_B);

  e8_prep<<<(NCWP + NROWS + 255) / 256, 256, 0, stream>>>(X, G, GN, Gb2, Xs, best);
  e8_main<<<dim3(RB, NCHUNK), 256, 0, stream>>>(Gb2, Xs, best);
  e8_final<<<NROWS / 256, 256, 0, stream>>>(G, best, out);
}